// Round 9
// baseline (320.267 us; speedup 1.0000x reference)
//
#include <hip/hip_runtime.h>

#define TT   512
#define HH   50
#define MB   8            // batch rows per block
#define NW   14           // waves: 7 A (layer 0) + 7 B (layer 1)
#define NTHR (NW * 64)    // 896 threads

typedef _Float16 f16x8 __attribute__((ext_vector_type(8)));
typedef float    f32x4 __attribute__((ext_vector_type(4)));

#define L2E 1.4426950408889634f

__device__ __forceinline__ float rcp_f(float v) { return __builtin_amdgcn_rcpf(v); }
__device__ __forceinline__ float ex2_f(float v) { return __builtin_amdgcn_exp2f(v); }

// Exact R5 gate math: g* already scaled (-log2e for i,f,o; +2log2e for g).
__device__ __forceinline__ float lstm_chain(float g0, float g1, float g2, float g3,
                                            float& cst) {
    float eI = ex2_f(g0), eF = ex2_f(g1), tG = ex2_f(g2), eO = ex2_f(g3);
    float dI = 1.0f + eI, dF = 1.0f + eF, dO = 1.0f + eO;
    float IG = (tG - 1.0f) * rcp_f(dI * (tG + 1.0f));
    float cn = __builtin_fmaf(rcp_f(dF), cst, IG);
    cst = cn;
    float cc = fminf(fmaxf(cn, -16.0f), 16.0f);
    float tc = ex2_f(cc * (2.0f * L2E));
    return (tc - 1.0f) * rcp_f(dO * (tc + 1.0f));
}

// Anti-phase producer/consumer pipeline, 2 barriers/step:
//   A waves (0-6, layer 0), each owns tiles 2w,2w+1 (8 units):
//     phase1: read h0(i-1), ISSUE a0(i) MFMAs (consumed next phase)
//     phase2: gates(i) from acc, write h0(i) (cols cb and cb+8 copy)
//   B waves (7-13, layer 1), tiles likewise:
//     phase1: gates a1(i-2) from acc (MFMA'd last phase2), write h1(i-2)
//     phase2: read h0(i-1), h1(i-2); ISSUE a1(i-1) MFMAs
// Each phase feeds both pipes: one group's VALU chain overlaps the other
// group's LDS/MFMA latency. Buffers: h0(i)->sh0[i&1], h1(i-2)->sh1[i&1].
// Lane (q,n): chain = (unit 8*wg + 4*(n>=8) + q, batch n&7); acc select a0/a1 tile
// by n&8 (tile-beta cols 8-15 read the col+8 h copies).
__global__ __launch_bounds__(NTHR, 1)
void lstm2_kernel(const float* __restrict__ x,
                  const float* __restrict__ W_ih0, const float* __restrict__ W_hh0,
                  const float* __restrict__ b_ih0, const float* __restrict__ b_hh0,
                  const float* __restrict__ W_ih1, const float* __restrict__ W_hh1,
                  const float* __restrict__ b_ih1, const float* __restrict__ b_hh1,
                  const float* __restrict__ W_fc,  const float* __restrict__ b_fc,
                  float* __restrict__ out)
{
    // h layout [buf][ki][q][col][e] f16; row k -> (ki=k>>5, q=(k>>3)&3, e=k&7).
    __shared__ __align__(16) _Float16 sh0[2][2][4][16][8];   // 4 KiB  h0
    __shared__ __align__(16) _Float16 sh1[2][2][4][16][8];   // 4 KiB  h1
    __shared__ float sh_x[MB][TT + 4];
    __shared__ float shf[MB][52];
    __shared__ float sh_wfc[HH];

    const int tid = threadIdx.x;
    const int w   = tid >> 6;
    const int l   = tid & 63;
    const int q   = l >> 4;
    const int n   = l & 15;
    const int b0  = blockIdx.x * MB;
    const bool isA = (w < 7);
    const int  wg  = isA ? w : (w - 7);

    for (int i = tid; i < 2 * 2 * 4 * 16 * 8; i += NTHR) {
        (&sh0[0][0][0][0][0])[i] = (_Float16)0.0f;
        (&sh1[0][0][0][0][0])[i] = (_Float16)0.0f;
    }
    for (int i = tid; i < MB * TT; i += NTHR)
        sh_x[i >> 9][i & (TT - 1)] = x[(size_t)b0 * TT + i];
    for (int i = tid; i < HH; i += NTHR) sh_wfc[i] = W_fc[i];

    // ---- weight fragments. A: wfA = W_hh0 (tiles 2wg,2wg+1). B: wfA = W_ih1,
    // wfB = W_hh1. A-row r=n -> unit 4*tile+(n>>2), gate n&3; pre-scaled.
    // k-map: k = ki*32 + q*8 + e (same bijection as B-frag layout -> sums correct).
    const float srow = ((n & 3) == 2) ? (2.0f * L2E) : (-L2E);
    f16x8 wfA[2][2], wfB[2][2];
    #pragma unroll
    for (int tt = 0; tt < 2; ++tt) {
        int tile = 2 * wg + tt;
        int ur   = 4 * tile + (n >> 2);
        bool rok = (ur < HH);
        int grow = (n & 3) * HH + (rok ? ur : 0);
        #pragma unroll
        for (int ki = 0; ki < 2; ++ki) {
            #pragma unroll
            for (int e = 0; e < 8; ++e) {
                int k = ki * 32 + q * 8 + e;
                bool ok = rok && (k < HH);
                float vA = 0.0f, vB = 0.0f;
                if (ok) {
                    if (isA) { vA = W_hh0[grow * HH + k]; }
                    else     { vA = W_ih1[grow * HH + k]; vB = W_hh1[grow * HH + k]; }
                }
                wfA[tt][ki][e] = (_Float16)(srow * vA);
                wfB[tt][ki][e] = (_Float16)(srow * vB);
            }
        }
    }

    // ---- chain identity ----
    const int  u  = 8 * wg + ((n & 8) ? 4 : 0) + q;
    const int  cb = n & 7;
    const bool wr = (u < HH);
    const int  uc = wr ? u : 0;

    float bz[4], wz[4];
    #pragma unroll
    for (int e = 0; e < 4; ++e) {
        int gr = e * HH + uc;
        float sc = (e == 2) ? (2.0f * L2E) : (-L2E);
        bz[e] = sc * (isA ? (b_ih0[gr] + b_hh0[gr]) : (b_ih1[gr] + b_hh1[gr]));
        wz[e] = isA ? (sc * W_ih0[gr]) : 0.0f;
    }

    const int uk = uc >> 5, uq2 = (uc >> 3) & 3, ue = uc & 7;
    _Float16* wpP0 = isA ? &sh0[0][uk][uq2][cb][ue] : &sh1[0][uk][uq2][cb][ue];
    _Float16* wpP1 = isA ? &sh0[1][uk][uq2][cb][ue] : &sh1[1][uk][uq2][cb][ue];

    const float* xq = &sh_x[cb][0];
    const f32x4 z = {0.0f, 0.0f, 0.0f, 0.0f};
    f32x4 acc0 = z, acc1 = z;    // A: a0 tiles alpha/beta; B: a1 tiles alpha/beta
    float cst = 0.0f;

    __syncthreads();

#define MFMA(A, B, C) __builtin_amdgcn_mfma_f32_16x16x32_f16((A), (B), (C), 0, 0, 0)

// phase1 of step i (P = i&1): A issues a0(i); B gates a1(i-2) (if BG), writes h1(i-2)->buf P
#define PHASE1(P, BG)                                                             \
    {                                                                             \
        if (isA) {                                                                \
            f16x8 hb0 = *(const f16x8*)&sh0[(P) ^ 1][0][q][n][0];                 \
            f16x8 hb1 = *(const f16x8*)&sh0[(P) ^ 1][1][q][n][0];                 \
            acc0 = MFMA(wfA[0][0], hb0, z);                                       \
            acc0 = MFMA(wfA[0][1], hb1, acc0);                                    \
            acc1 = MFMA(wfA[1][0], hb0, z);                                       \
            acc1 = MFMA(wfA[1][1], hb1, acc1);                                    \
        } else if (BG) {                                                          \
            float g0 = ((n & 8) ? acc1[0] : acc0[0]) + bz[0];                     \
            float g1 = ((n & 8) ? acc1[1] : acc0[1]) + bz[1];                     \
            float g2 = ((n & 8) ? acc1[2] : acc0[2]) + bz[2];                     \
            float g3 = ((n & 8) ? acc1[3] : acc0[3]) + bz[3];                     \
            float hv = lstm_chain(g0, g1, g2, g3, cst);                           \
            if (wr) {                                                             \
                _Float16 h16 = (_Float16)hv;                                      \
                _Float16* wp = (P) ? wpP1 : wpP0;                                 \
                wp[0] = h16; wp[64] = h16;                                        \
            }                                                                     \
        }                                                                         \
        __syncthreads();                                                          \
    }

// phase2 of step i (P = i&1): A gates(i) + write h0(i)->buf P; B issues a1(i-1)
#define PHASE2(P, XI)                                                             \
    {                                                                             \
        if (isA) {                                                                \
            float xi = (XI);                                                      \
            float g0 = __builtin_fmaf(xi, wz[0], ((n & 8) ? acc1[0] : acc0[0]) + bz[0]); \
            float g1 = __builtin_fmaf(xi, wz[1], ((n & 8) ? acc1[1] : acc0[1]) + bz[1]); \
            float g2 = __builtin_fmaf(xi, wz[2], ((n & 8) ? acc1[2] : acc0[2]) + bz[2]); \
            float g3 = __builtin_fmaf(xi, wz[3], ((n & 8) ? acc1[3] : acc0[3]) + bz[3]); \
            float hv = lstm_chain(g0, g1, g2, g3, cst);                           \
            if (wr) {                                                             \
                _Float16 h16 = (_Float16)hv;                                      \
                _Float16* wp = (P) ? wpP1 : wpP0;                                 \
                wp[0] = h16; wp[64] = h16;                                        \
            }                                                                     \
        } else {                                                                  \
            f16x8 hb0 = *(const f16x8*)&sh0[(P) ^ 1][0][q][n][0];                 \
            f16x8 hb1 = *(const f16x8*)&sh0[(P) ^ 1][1][q][n][0];                 \
            f16x8 pb0 = *(const f16x8*)&sh1[P][0][q][n][0];                       \
            f16x8 pb1 = *(const f16x8*)&sh1[P][1][q][n][0];                       \
            acc0 = MFMA(wfA[0][0], hb0, z);                                       \
            acc0 = MFMA(wfA[0][1], hb1, acc0);                                    \
            acc0 = MFMA(wfB[0][0], pb0, acc0);                                    \
            acc0 = MFMA(wfB[0][1], pb1, acc0);                                    \
            acc1 = MFMA(wfA[1][0], hb0, z);                                       \
            acc1 = MFMA(wfA[1][1], hb1, acc1);                                    \
            acc1 = MFMA(wfB[1][0], pb0, acc1);                                    \
            acc1 = MFMA(wfB[1][1], pb1, acc1);                                    \
        }                                                                         \
        __syncthreads();                                                          \
    }

    // ---- peel i=0,1 (B gates skipped: no valid acc yet) ----
    PHASE1(0, 0) PHASE2(0, xq[0])     // i=0: A h0(0)->buf0; B mfma a1(-1) (zeros)
    PHASE1(1, 0) PHASE2(1, xq[1])     // i=1: A h0(1)->buf1; B mfma a1(0)

    // ---- main i=2..511 (255 even/odd pairs) ----
    for (int k2 = 0; k2 < 255; ++k2) {
        PHASE1(0, 1) PHASE2(0, xq[2])
        PHASE1(1, 1) PHASE2(1, xq[3])
        xq += 2;
    }
#undef PHASE1
#undef PHASE2

    // ---- epilogue: B finishes h1(510), then a1(511)+h1(511)->shf ----
    if (!isA) {   // gates a1(510) -> h1(510) -> buf0 (i=512 parity)
        float g0 = ((n & 8) ? acc1[0] : acc0[0]) + bz[0];
        float g1 = ((n & 8) ? acc1[1] : acc0[1]) + bz[1];
        float g2 = ((n & 8) ? acc1[2] : acc0[2]) + bz[2];
        float g3 = ((n & 8) ? acc1[3] : acc0[3]) + bz[3];
        float hv = lstm_chain(g0, g1, g2, g3, cst);
        if (wr) { _Float16 h16 = (_Float16)hv; wpP0[0] = h16; wpP0[64] = h16; }
    }
    __syncthreads();
    if (!isA) {   // a1(511) from h0(511) (buf1) + h1(510) (buf0); gates -> shf
        f16x8 hb0 = *(const f16x8*)&sh0[1][0][q][n][0];
        f16x8 hb1 = *(const f16x8*)&sh0[1][1][q][n][0];
        f16x8 pb0 = *(const f16x8*)&sh1[0][0][q][n][0];
        f16x8 pb1 = *(const f16x8*)&sh1[0][1][q][n][0];
        acc0 = MFMA(wfA[0][0], hb0, z);
        acc0 = MFMA(wfA[0][1], hb1, acc0);
        acc0 = MFMA(wfB[0][0], pb0, acc0);
        acc0 = MFMA(wfB[0][1], pb1, acc0);
        acc1 = MFMA(wfA[1][0], hb0, z);
        acc1 = MFMA(wfA[1][1], hb1, acc1);
        acc1 = MFMA(wfB[1][0], pb0, acc1);
        acc1 = MFMA(wfB[1][1], pb1, acc1);
        float g0 = ((n & 8) ? acc1[0] : acc0[0]) + bz[0];
        float g1 = ((n & 8) ? acc1[1] : acc0[1]) + bz[1];
        float g2 = ((n & 8) ? acc1[2] : acc0[2]) + bz[2];
        float g3 = ((n & 8) ? acc1[3] : acc0[3]) + bz[3];
        float hv = lstm_chain(g0, g1, g2, g3, cst);
        if (wr) shf[cb][uc] = hv;
    }
    __syncthreads();

    if (tid < MB) {
        float s = b_fc[0];
        for (int j = 0; j < HH; ++j) s += shf[tid][j] * sh_wfc[j];
        out[b0 + tid] = s;
    }
#undef MFMA
}

extern "C" void kernel_launch(void* const* d_in, const int* in_sizes, int n_in,
                              void* d_out, int out_size, void* d_ws, size_t ws_size,
                              hipStream_t stream) {
    const float* xin   = (const float*)d_in[0];
    const float* W_ih0 = (const float*)d_in[1];
    const float* W_hh0 = (const float*)d_in[2];
    const float* b_ih0 = (const float*)d_in[3];
    const float* b_hh0 = (const float*)d_in[4];
    const float* W_ih1 = (const float*)d_in[5];
    const float* W_hh1 = (const float*)d_in[6];
    const float* b_ih1 = (const float*)d_in[7];
    const float* b_hh1 = (const float*)d_in[8];
    const float* W_fc  = (const float*)d_in[9];
    const float* b_fc  = (const float*)d_in[10];
    float* out = (float*)d_out;

    lstm2_kernel<<<dim3(2048 / MB), dim3(NTHR), 0, stream>>>(
        xin, W_ih0, W_hh0, b_ih0, b_hh0, W_ih1, W_hh1, b_ih1, b_hh1, W_fc, b_fc, out);
}